// Round 6
// baseline (68.466 us; speedup 1.0000x reference)
//
#include <hip/hip_runtime.h>
#include <cmath>

// Problem constants: B=4, T=1, DIN=4096, DOUT=11008, RANK=512
constexpr int DIN  = 4096;
constexpr int DOUT = 11008;
constexpr int RANK = 512;
constexpr int NB   = 4;

constexpr int NCHUNK = 256;          // d-chunks for lr partials
constexpr int DCH    = DIN / NCHUNK; // 16 d's per chunk

constexpr int NSL = 16;              // k-slices (split-K)
constexpr int SL4 = 64;              // float4 per slice = one lane-stride
constexpr int RPW = 4;               // rows per wave
constexpr int ROWS_PER_BLOCK = 4 * RPW; // 16

// ---------------------------------------------------------------------------
// Phase 1 (fused prep): xs[b][d] = x*mask -> ws;  xc = x*(1-mask) -> LDS;
// partial[chunk][b][r] = sum_{d in chunk} xc[b][d] * V[d][r]
// ---------------------------------------------------------------------------
__global__ __launch_bounds__(512)
void lr_partial_kernel(const float* __restrict__ x,
                       const float* __restrict__ scale,
                       const float* __restrict__ thp,
                       const float* __restrict__ V,
                       float* __restrict__ partial,
                       float* __restrict__ xs)
{
    __shared__ float xc[NB * DCH];
    const int chunk = blockIdx.x;
    const int t = threadIdx.x;
    const float th = thp[0];
    if (t < NB * DCH) {
        const int b = t / DCH, dd = t % DCH;
        const int d = chunk * DCH + dd;
        const float xv = x[b * DIN + d];
        const bool keep = fabsf(xv * scale[d]) > th; // mask==1 -> sparse path
        xc[t] = keep ? 0.f : xv;
        xs[b * DIN + d] = keep ? xv : 0.f;
    }
    __syncthreads();
    const int r = t; // 0..511
    float a0 = 0.f, a1 = 0.f, a2 = 0.f, a3 = 0.f;
    #pragma unroll
    for (int dd = 0; dd < DCH; ++dd) {
        const float v = V[(size_t)(chunk * DCH + dd) * RANK + r];
        a0 = fmaf(xc[0 * DCH + dd], v, a0);
        a1 = fmaf(xc[1 * DCH + dd], v, a1);
        a2 = fmaf(xc[2 * DCH + dd], v, a2);
        a3 = fmaf(xc[3 * DCH + dd], v, a3);
    }
    float* p = partial + (size_t)chunk * (NB * RANK) + r;
    p[0 * RANK] = a0;
    p[1 * RANK] = a1;
    p[2 * RANK] = a2;
    p[3 * RANK] = a3;
}

// ---------------------------------------------------------------------------
// Phase 2: lr[b][r] = S[r] * sum_chunk partial[chunk][b][r]
// ---------------------------------------------------------------------------
__global__ __launch_bounds__(256)
void lr_reduce_kernel(const float* __restrict__ partial,
                      const float* __restrict__ S,
                      float* __restrict__ lr)
{
    const int t = blockIdx.x * 256 + threadIdx.x;
    const int idx = t >> 4;  // output index 0..NB*RANK-1
    const int s = t & 15;    // chunk-subset
    float sum = 0.f;
    #pragma unroll
    for (int j = 0; j < 16; ++j)
        sum += partial[(size_t)(s * 16 + j) * (NB * RANK) + idx];
    #pragma unroll
    for (int m = 8; m >= 1; m >>= 1)
        sum += __shfl_xor(sum, m, 64);
    if (s == 0)
        lr[idx] = sum * S[idx & (RANK - 1)];
}

// ---------------------------------------------------------------------------
// Main (k-slice split): part[s][b][o] = sum_{d in slice s} xs[b][d]*W[o][d]
//                       (+ U.lr term added by s==0)
// Block = 4 waves x 4 rows, ONE slice (blockIdx.y). Lane owns column
// c = s*64+lane; xs lives in 4 float4 registers; block xs footprint = 4 KB
// -> L1-resident. Inner VMEM = pure W stream (4 coalesced float4/wave).
// No LDS, ~60 VGPR -> 8 waves/SIMD.
// ---------------------------------------------------------------------------
__global__ __launch_bounds__(256)
void rsparse_main_kernel(const float* __restrict__ xs,
                         const float* __restrict__ W,
                         const float* __restrict__ U,
                         const float* __restrict__ lr,
                         float* __restrict__ part)
{
    const int tid  = threadIdx.x;
    const int wave = tid >> 6, lane = tid & 63;
    const int s  = blockIdx.y;
    const int o0 = blockIdx.x * ROWS_PER_BLOCK + wave * RPW;
    const int c  = s * SL4 + lane; // float4 column index, 0..1023

    const float4* __restrict__ XSg = (const float4*)xs; // [NB][1024]
    float4 xr[NB];
    #pragma unroll
    for (int b = 0; b < NB; ++b)
        xr[b] = XSg[b * (DIN / 4) + c];

    // W loads: 4 independent coalesced float4 streams
    float4 w[RPW];
    #pragma unroll
    for (int r = 0; r < RPW; ++r)
        w[r] = ((const float4*)(W + (size_t)(o0 + r) * DIN))[c];

    float acc[RPW][NB] = {};
    #pragma unroll
    for (int r = 0; r < RPW; ++r) {
        #pragma unroll
        for (int b = 0; b < NB; ++b) {
            acc[r][b] = fmaf(w[r].x, xr[b].x, acc[r][b]);
            acc[r][b] = fmaf(w[r].y, xr[b].y, acc[r][b]);
            acc[r][b] = fmaf(w[r].z, xr[b].z, acc[r][b]);
            acc[r][b] = fmaf(w[r].w, xr[b].w, acc[r][b]);
        }
    }

    if (s == 0) { // U.lr compensation, once per output row
        const float4* __restrict__ LR = (const float4*)lr; // [NB][128]
        #pragma unroll
        for (int r = 0; r < RPW; ++r) {
            const float4* __restrict__ Ur = (const float4*)(U + (size_t)(o0 + r) * RANK);
            const float4 u0 = Ur[lane];
            const float4 u1 = Ur[64 + lane];
            #pragma unroll
            for (int b = 0; b < NB; ++b) {
                const float4 l0 = LR[b * 128 + lane];
                const float4 l1 = LR[b * 128 + 64 + lane];
                acc[r][b] = fmaf(u0.x, l0.x, acc[r][b]);
                acc[r][b] = fmaf(u0.y, l0.y, acc[r][b]);
                acc[r][b] = fmaf(u0.z, l0.z, acc[r][b]);
                acc[r][b] = fmaf(u0.w, l0.w, acc[r][b]);
                acc[r][b] = fmaf(u1.x, l1.x, acc[r][b]);
                acc[r][b] = fmaf(u1.y, l1.y, acc[r][b]);
                acc[r][b] = fmaf(u1.z, l1.z, acc[r][b]);
                acc[r][b] = fmaf(u1.w, l1.w, acc[r][b]);
            }
        }
    }

    // 64-lane butterfly reduction per (row, batch)
    #pragma unroll
    for (int r = 0; r < RPW; ++r)
        #pragma unroll
        for (int b = 0; b < NB; ++b)
            #pragma unroll
            for (int m = 32; m >= 1; m >>= 1)
                acc[r][b] += __shfl_xor(acc[r][b], m, 64);

    if (lane == 0) {
        float* p = part + (size_t)s * (NB * DOUT);
        #pragma unroll
        for (int r = 0; r < RPW; ++r)
            #pragma unroll
            for (int b = 0; b < NB; ++b)
                p[b * DOUT + o0 + r] = acc[r][b];
    }
}

// ---------------------------------------------------------------------------
// Final: out[b][o] = sum_s part[s][b][o] + bias[o]
// 4 threads per float4-output, each sums 4 slices; width-4 shfl reduce.
// grid = NB*DOUT threads / 256 = 172 blocks
// ---------------------------------------------------------------------------
__global__ __launch_bounds__(256)
void final_add_kernel(const float* __restrict__ part,
                      const float* __restrict__ bias,
                      float* __restrict__ out)
{
    const int t  = blockIdx.x * 256 + threadIdx.x;
    const int i4 = t >> 2;      // float4 output index, 0..NB*DOUT/4-1
    const int q  = t & 3;       // slice quarter
    const float4* p4 = (const float4*)part;
    const int stride4 = NB * DOUT / 4;

    float4 sum = {0.f, 0.f, 0.f, 0.f};
    #pragma unroll
    for (int j = 0; j < 4; ++j) {
        const float4 v = p4[(size_t)(q * 4 + j) * stride4 + i4];
        sum.x += v.x; sum.y += v.y; sum.z += v.z; sum.w += v.w;
    }
    #pragma unroll
    for (int m = 1; m <= 2; m <<= 1) {
        sum.x += __shfl_xor(sum.x, m, 64);
        sum.y += __shfl_xor(sum.y, m, 64);
        sum.z += __shfl_xor(sum.z, m, 64);
        sum.w += __shfl_xor(sum.w, m, 64);
    }
    if (q == 0) {
        const int o4 = i4 % (DOUT / 4);
        const float4 bv = ((const float4*)bias)[o4];
        float4 r;
        r.x = sum.x + bv.x;
        r.y = sum.y + bv.y;
        r.z = sum.z + bv.z;
        r.w = sum.w + bv.w;
        ((float4*)out)[i4] = r;
    }
}

// ---------------------------------------------------------------------------
extern "C" void kernel_launch(void* const* d_in, const int* in_sizes, int n_in,
                              void* d_out, int out_size, void* d_ws, size_t ws_size,
                              hipStream_t stream)
{
    const float* x     = (const float*)d_in[0]; // [4][1][4096]
    const float* W     = (const float*)d_in[1]; // [11008][4096]
    const float* bias  = (const float*)d_in[2]; // [11008]
    const float* U     = (const float*)d_in[3]; // [11008][512]
    const float* S     = (const float*)d_in[4]; // [512]
    const float* V     = (const float*)d_in[5]; // [4096][512]
    const float* scale = (const float*)d_in[6]; // [4096]
    const float* thp   = (const float*)d_in[7]; // [1]
    float* out = (float*)d_out;                 // [4][1][11008]

    float* partial = (float*)d_ws;                          // 2 MB
    float* lr      = partial + (size_t)NCHUNK * NB * RANK;  // 8 KB
    float* xs      = lr + NB * RANK;                        // 64 KB
    float* part    = xs + NB * DIN;                         // NSL*NB*DOUT f32 = 2.8 MB

    lr_partial_kernel<<<NCHUNK, 512, 0, stream>>>(x, scale, thp, V, partial, xs);
    lr_reduce_kernel<<<(NB * RANK * 16) / 256, 256, 0, stream>>>(partial, S, lr);

    dim3 grid(DOUT / ROWS_PER_BLOCK, NSL); // (688, 16)
    rsparse_main_kernel<<<grid, 256, 0, stream>>>(xs, W, U, lr, part);
    final_add_kernel<<<(NB * DOUT) / 256, 256, 0, stream>>>(part, bias, out);
}

// Round 7
// 65.990 us; speedup vs baseline: 1.0375x; 1.0375x over previous
//
#include <hip/hip_runtime.h>
#include <cmath>

// Problem constants: B=4, T=1, DIN=4096, DOUT=11008, RANK=512
constexpr int DIN  = 4096;
constexpr int DOUT = 11008;
constexpr int RANK = 512;
constexpr int NB   = 4;

constexpr int NCHUNK = 256;          // d-chunks for lr partials
constexpr int DCH    = DIN / NCHUNK; // 16 d's per chunk

constexpr int NSL = 32;              // k-slices (split-K)
constexpr int SL4 = DIN / NSL / 4;   // 32 float4 per slice per row
constexpr int USL = 8;               // slices 0..7 also handle U.lr (64 r's each)
constexpr int UR4 = RANK / USL / 4;  // 16 float4 of U per slice

// ---------------------------------------------------------------------------
// Phase 1 (fused prep): xs[b][d] = x*mask -> ws;  xc = x*(1-mask) -> LDS;
// partial[chunk][b][r] = sum_{d in chunk} xc[b][d] * V[d][r]
// ---------------------------------------------------------------------------
__global__ __launch_bounds__(512)
void lr_partial_kernel(const float* __restrict__ x,
                       const float* __restrict__ scale,
                       const float* __restrict__ thp,
                       const float* __restrict__ V,
                       float* __restrict__ partial,
                       float* __restrict__ xs)
{
    __shared__ float xc[NB * DCH];
    const int chunk = blockIdx.x;
    const int t = threadIdx.x;
    const float th = thp[0];
    if (t < NB * DCH) {
        const int b = t / DCH, dd = t % DCH;
        const int d = chunk * DCH + dd;
        const float xv = x[b * DIN + d];
        const bool keep = fabsf(xv * scale[d]) > th; // mask==1 -> sparse path
        xc[t] = keep ? 0.f : xv;
        xs[b * DIN + d] = keep ? xv : 0.f;
    }
    __syncthreads();
    const int r = t; // 0..511
    float a0 = 0.f, a1 = 0.f, a2 = 0.f, a3 = 0.f;
    #pragma unroll
    for (int dd = 0; dd < DCH; ++dd) {
        const float v = V[(size_t)(chunk * DCH + dd) * RANK + r];
        a0 = fmaf(xc[0 * DCH + dd], v, a0);
        a1 = fmaf(xc[1 * DCH + dd], v, a1);
        a2 = fmaf(xc[2 * DCH + dd], v, a2);
        a3 = fmaf(xc[3 * DCH + dd], v, a3);
    }
    float* p = partial + (size_t)chunk * (NB * RANK) + r;
    p[0 * RANK] = a0;
    p[1 * RANK] = a1;
    p[2 * RANK] = a2;
    p[3 * RANK] = a3;
}

// ---------------------------------------------------------------------------
// Phase 2: lr[b][r] = S[r] * sum_chunk partial[chunk][b][r]
// ---------------------------------------------------------------------------
__global__ __launch_bounds__(256)
void lr_reduce_kernel(const float* __restrict__ partial,
                      const float* __restrict__ S,
                      float* __restrict__ lr)
{
    const int t = blockIdx.x * 256 + threadIdx.x;
    const int idx = t >> 4;  // output index 0..NB*RANK-1
    const int s = t & 15;    // chunk-subset
    float sum = 0.f;
    #pragma unroll
    for (int j = 0; j < 16; ++j)
        sum += partial[(size_t)(s * 16 + j) * (NB * RANK) + idx];
    #pragma unroll
    for (int m = 8; m >= 1; m >>= 1)
        sum += __shfl_xor(sum, m, 64);
    if (s == 0)
        lr[idx] = sum * S[idx & (RANK - 1)];
}

// ---------------------------------------------------------------------------
// Main (transposed GEMV): thread owns ONE output row o; slice s of K.
//   part[s][b][o] = sum_{d in slice s} xs[b][d] * W[o][d]
//                   (+ sum_{r in r-slice} lr[b][r]*U[o][r] for s < USL)
// xs/lr addresses are threadIdx-free -> wave-uniform -> scalar-cache loads.
// W: per-lane linear float4 stream, immediate offsets, 32 loads in flight.
// NO cross-lane reduction; 4 coalesced stores per thread.
// grid (DOUT/256, NSL) = (43, 32), block 256.
// ---------------------------------------------------------------------------
__global__ __launch_bounds__(256)
void rsparse_main_kernel(const float* __restrict__ xs,
                         const float* __restrict__ W,
                         const float* __restrict__ U,
                         const float* __restrict__ lr,
                         float* __restrict__ part)
{
    const int o = blockIdx.x * 256 + threadIdx.x;
    const int s = blockIdx.y;

    const float4* __restrict__ Wr = (const float4*)(W + (size_t)o * DIN) + s * SL4;
    const float*  xsb = xs + s * (DIN / NSL); // + b*DIN + 4*k, uniform

    float acc[NB] = {0.f, 0.f, 0.f, 0.f};

    #pragma unroll
    for (int k = 0; k < SL4; ++k) {
        const float4 w = Wr[k];
        #pragma unroll
        for (int b = 0; b < NB; ++b) {
            const float4 xv = *(const float4*)(xsb + b * DIN + 4 * k);
            acc[b] = fmaf(w.x, xv.x, acc[b]);
            acc[b] = fmaf(w.y, xv.y, acc[b]);
            acc[b] = fmaf(w.z, xv.z, acc[b]);
            acc[b] = fmaf(w.w, xv.w, acc[b]);
        }
    }

    if (s < USL) { // U.lr compensation, r-slice s*64..s*64+63
        const float4* __restrict__ Ur = (const float4*)(U + (size_t)o * RANK) + s * UR4;
        const float* lrb = lr + s * (RANK / USL); // + b*RANK + 4*k, uniform
        #pragma unroll
        for (int k = 0; k < UR4; ++k) {
            const float4 u = Ur[k];
            #pragma unroll
            for (int b = 0; b < NB; ++b) {
                const float4 lv = *(const float4*)(lrb + b * RANK + 4 * k);
                acc[b] = fmaf(u.x, lv.x, acc[b]);
                acc[b] = fmaf(u.y, lv.y, acc[b]);
                acc[b] = fmaf(u.z, lv.z, acc[b]);
                acc[b] = fmaf(u.w, lv.w, acc[b]);
            }
        }
    }

    float* p = part + (size_t)s * (NB * DOUT) + o;
    #pragma unroll
    for (int b = 0; b < NB; ++b)
        p[b * DOUT] = acc[b];
}

// ---------------------------------------------------------------------------
// Final: out[b][o] = sum_s part[s][b][o] + bias[o]
// 1 thread per output; 32 independent strided loads (coalesced within wave).
// grid = NB*DOUT/256 = 172 blocks
// ---------------------------------------------------------------------------
__global__ __launch_bounds__(256)
void final_add_kernel(const float* __restrict__ part,
                      const float* __restrict__ bias,
                      float* __restrict__ out)
{
    const int i = blockIdx.x * 256 + threadIdx.x; // 0..NB*DOUT-1 (= b*DOUT+o)
    const int o = i % DOUT;
    float sum = 0.f;
    #pragma unroll
    for (int s = 0; s < NSL; ++s)
        sum += part[(size_t)s * (NB * DOUT) + i];
    out[i] = sum + bias[o];
}

// ---------------------------------------------------------------------------
extern "C" void kernel_launch(void* const* d_in, const int* in_sizes, int n_in,
                              void* d_out, int out_size, void* d_ws, size_t ws_size,
                              hipStream_t stream)
{
    const float* x     = (const float*)d_in[0]; // [4][1][4096]
    const float* W     = (const float*)d_in[1]; // [11008][4096]
    const float* bias  = (const float*)d_in[2]; // [11008]
    const float* U     = (const float*)d_in[3]; // [11008][512]
    const float* S     = (const float*)d_in[4]; // [512]
    const float* V     = (const float*)d_in[5]; // [4096][512]
    const float* scale = (const float*)d_in[6]; // [4096]
    const float* thp   = (const float*)d_in[7]; // [1]
    float* out = (float*)d_out;                 // [4][1][11008]

    float* partial = (float*)d_ws;                          // 2 MB
    float* lr      = partial + (size_t)NCHUNK * NB * RANK;  // 8 KB
    float* xs      = lr + NB * RANK;                        // 64 KB
    float* part    = xs + NB * DIN;                         // NSL*NB*DOUT f32 = 5.6 MB

    lr_partial_kernel<<<NCHUNK, 512, 0, stream>>>(x, scale, thp, V, partial, xs);
    lr_reduce_kernel<<<(NB * RANK * 16) / 256, 256, 0, stream>>>(partial, S, lr);

    dim3 grid(DOUT / 256, NSL); // (43, 32)
    rsparse_main_kernel<<<grid, 256, 0, stream>>>(xs, W, U, lr, part);
    final_add_kernel<<<(NB * DOUT) / 256, 256, 0, stream>>>(part, bias, out);
}

// Round 8
// 54.392 us; speedup vs baseline: 1.2588x; 1.2132x over previous
//
#include <hip/hip_runtime.h>
#include <cmath>

// Problem constants: B=4, T=1, DIN=4096, DOUT=11008, RANK=512
constexpr int DIN  = 4096;
constexpr int DOUT = 11008;
constexpr int RANK = 512;
constexpr int NB   = 4;

constexpr int NCHUNK = 256;          // d-chunks for lr partials
constexpr int DCH    = DIN / NCHUNK; // 16 d's per chunk
constexpr int SPLITK = 2;
constexpr int KHALF4 = DIN / SPLITK / 4; // 512 float4 per k-half
constexpr int RPW    = 4;            // rows per wave
constexpr int ROWS_PER_BLOCK = 4 * RPW; // 16

// ---------------------------------------------------------------------------
// Phase 1 (fused prep): xs[b][d] = x*mask -> ws;  xc = x*(1-mask) -> LDS;
// partial[chunk][b][r] = sum_{d in chunk} xc[b][d] * V[d][r]
// ---------------------------------------------------------------------------
__global__ __launch_bounds__(512)
void lr_partial_kernel(const float* __restrict__ x,
                       const float* __restrict__ scale,
                       const float* __restrict__ thp,
                       const float* __restrict__ V,
                       float* __restrict__ partial,
                       float* __restrict__ xs)
{
    __shared__ float xc[NB * DCH];
    const int chunk = blockIdx.x;
    const int t = threadIdx.x;
    const float th = thp[0];
    if (t < NB * DCH) {
        const int b = t / DCH, dd = t % DCH;
        const int d = chunk * DCH + dd;
        const float xv = x[b * DIN + d];
        const bool keep = fabsf(xv * scale[d]) > th; // mask==1 -> sparse path
        xc[t] = keep ? 0.f : xv;
        xs[b * DIN + d] = keep ? xv : 0.f;
    }
    __syncthreads();
    const int r = t; // 0..511
    float a0 = 0.f, a1 = 0.f, a2 = 0.f, a3 = 0.f;
    #pragma unroll
    for (int dd = 0; dd < DCH; ++dd) {
        const float v = V[(size_t)(chunk * DCH + dd) * RANK + r];
        a0 = fmaf(xc[0 * DCH + dd], v, a0);
        a1 = fmaf(xc[1 * DCH + dd], v, a1);
        a2 = fmaf(xc[2 * DCH + dd], v, a2);
        a3 = fmaf(xc[3 * DCH + dd], v, a3);
    }
    float* p = partial + (size_t)chunk * (NB * RANK) + r;
    p[0 * RANK] = a0;
    p[1 * RANK] = a1;
    p[2 * RANK] = a2;
    p[3 * RANK] = a3;
}

// ---------------------------------------------------------------------------
// Phase 2: lr[b][r] = S[r] * sum_chunk partial[chunk][b][r]
// ---------------------------------------------------------------------------
__global__ __launch_bounds__(256)
void lr_reduce_kernel(const float* __restrict__ partial,
                      const float* __restrict__ S,
                      float* __restrict__ lr)
{
    const int t = blockIdx.x * 256 + threadIdx.x;
    const int idx = t >> 4;  // output index 0..NB*RANK-1
    const int s = t & 15;    // chunk-subset
    float sum = 0.f;
    #pragma unroll
    for (int j = 0; j < 16; ++j)
        sum += partial[(size_t)(s * 16 + j) * (NB * RANK) + idx];
    #pragma unroll
    for (int m = 8; m >= 1; m >>= 1)
        sum += __shfl_xor(sum, m, 64);
    if (s == 0)
        lr[idx] = sum * S[idx & (RANK - 1)];
}

// ---------------------------------------------------------------------------
// Main (split-K=2, R=4 rows/wave, register xs, NO LDS):
//   part[kh][b][o] = sum_{d in half kh} xs[b][d]*W[o][d]  (+ U.lr for kh==0)
// Per iter: 4 coalesced W float4 + 4 xs float4 (L1-hit) + 64 FMA.
// Block = 4 waves x 4 rows = 16 rows, one k-half; grid (688, 2) = 5504 waves.
// ---------------------------------------------------------------------------
__global__ __launch_bounds__(256)
void rsparse_main_kernel(const float* __restrict__ xs,
                         const float* __restrict__ W,
                         const float* __restrict__ U,
                         const float* __restrict__ lr,
                         float* __restrict__ part)
{
    const int tid  = threadIdx.x;
    const int wave = tid >> 6, lane = tid & 63;
    const int kh   = blockIdx.y;
    const int o0   = (blockIdx.x * 4 + wave) * RPW;

    const float4* __restrict__ W0 = (const float4*)(W + (size_t)(o0 + 0) * DIN) + kh * KHALF4;
    const float4* __restrict__ W1 = (const float4*)(W + (size_t)(o0 + 1) * DIN) + kh * KHALF4;
    const float4* __restrict__ W2 = (const float4*)(W + (size_t)(o0 + 2) * DIN) + kh * KHALF4;
    const float4* __restrict__ W3 = (const float4*)(W + (size_t)(o0 + 3) * DIN) + kh * KHALF4;
    const float4* __restrict__ XS = (const float4*)xs; // [NB][1024]
    const int xbase = kh * KHALF4;

    float acc[RPW][NB] = {};

    #pragma unroll 2
    for (int k = 0; k < 8; ++k) {
        const int c = (k << 6) + lane; // 0..511 within half
        const float4 w0 = W0[c];
        const float4 w1 = W1[c];
        const float4 w2 = W2[c];
        const float4 w3 = W3[c];
        #pragma unroll
        for (int b = 0; b < NB; ++b) {
            const float4 xv = XS[b * 1024 + xbase + c];
            acc[0][b] = fmaf(w0.x, xv.x, acc[0][b]);
            acc[0][b] = fmaf(w0.y, xv.y, acc[0][b]);
            acc[0][b] = fmaf(w0.z, xv.z, acc[0][b]);
            acc[0][b] = fmaf(w0.w, xv.w, acc[0][b]);
            acc[1][b] = fmaf(w1.x, xv.x, acc[1][b]);
            acc[1][b] = fmaf(w1.y, xv.y, acc[1][b]);
            acc[1][b] = fmaf(w1.z, xv.z, acc[1][b]);
            acc[1][b] = fmaf(w1.w, xv.w, acc[1][b]);
            acc[2][b] = fmaf(w2.x, xv.x, acc[2][b]);
            acc[2][b] = fmaf(w2.y, xv.y, acc[2][b]);
            acc[2][b] = fmaf(w2.z, xv.z, acc[2][b]);
            acc[2][b] = fmaf(w2.w, xv.w, acc[2][b]);
            acc[3][b] = fmaf(w3.x, xv.x, acc[3][b]);
            acc[3][b] = fmaf(w3.y, xv.y, acc[3][b]);
            acc[3][b] = fmaf(w3.z, xv.z, acc[3][b]);
            acc[3][b] = fmaf(w3.w, xv.w, acc[3][b]);
        }
    }

    if (kh == 0) { // U.lr term once per o-group
        const float4* __restrict__ U0 = (const float4*)(U + (size_t)(o0 + 0) * RANK);
        const float4* __restrict__ U1 = (const float4*)(U + (size_t)(o0 + 1) * RANK);
        const float4* __restrict__ U2 = (const float4*)(U + (size_t)(o0 + 2) * RANK);
        const float4* __restrict__ U3 = (const float4*)(U + (size_t)(o0 + 3) * RANK);
        const float4* __restrict__ LR = (const float4*)lr; // [NB][128]
        #pragma unroll
        for (int j = 0; j < 2; ++j) {
            const int c = (j << 6) + lane; // 0..127
            const float4 u0 = U0[c];
            const float4 u1 = U1[c];
            const float4 u2 = U2[c];
            const float4 u3 = U3[c];
            #pragma unroll
            for (int b = 0; b < NB; ++b) {
                const float4 lv = LR[b * 128 + c];
                acc[0][b] = fmaf(u0.x, lv.x, acc[0][b]);
                acc[0][b] = fmaf(u0.y, lv.y, acc[0][b]);
                acc[0][b] = fmaf(u0.z, lv.z, acc[0][b]);
                acc[0][b] = fmaf(u0.w, lv.w, acc[0][b]);
                acc[1][b] = fmaf(u1.x, lv.x, acc[1][b]);
                acc[1][b] = fmaf(u1.y, lv.y, acc[1][b]);
                acc[1][b] = fmaf(u1.z, lv.z, acc[1][b]);
                acc[1][b] = fmaf(u1.w, lv.w, acc[1][b]);
                acc[2][b] = fmaf(u2.x, lv.x, acc[2][b]);
                acc[2][b] = fmaf(u2.y, lv.y, acc[2][b]);
                acc[2][b] = fmaf(u2.z, lv.z, acc[2][b]);
                acc[2][b] = fmaf(u2.w, lv.w, acc[2][b]);
                acc[3][b] = fmaf(u3.x, lv.x, acc[3][b]);
                acc[3][b] = fmaf(u3.y, lv.y, acc[3][b]);
                acc[3][b] = fmaf(u3.z, lv.z, acc[3][b]);
                acc[3][b] = fmaf(u3.w, lv.w, acc[3][b]);
            }
        }
    }

    // 64-lane butterfly reduction
    #pragma unroll
    for (int r = 0; r < RPW; ++r)
        #pragma unroll
        for (int b = 0; b < NB; ++b)
            #pragma unroll
            for (int m = 32; m >= 1; m >>= 1)
                acc[r][b] += __shfl_xor(acc[r][b], m, 64);

    if (lane == 0) {
        float* p = part + (size_t)kh * (NB * DOUT);
        #pragma unroll
        for (int r = 0; r < RPW; ++r)
            #pragma unroll
            for (int b = 0; b < NB; ++b)
                p[b * DOUT + o0 + r] = acc[r][b];
    }
}

// ---------------------------------------------------------------------------
// Final: out[b][o] = part[0][b][o] + part[1][b][o] + bias[o]  (float4)
// ---------------------------------------------------------------------------
__global__ __launch_bounds__(256)
void final_add_kernel(const float* __restrict__ part,
                      const float* __restrict__ bias,
                      float* __restrict__ out)
{
    const int i4 = blockIdx.x * 256 + threadIdx.x; // 0..NB*DOUT/4-1
    const int o4 = i4 % (DOUT / 4);
    const float4 p0 = ((const float4*)part)[i4];
    const float4 p1 = ((const float4*)part)[NB * DOUT / 4 + i4];
    const float4 bv = ((const float4*)bias)[o4];
    float4 r;
    r.x = p0.x + p1.x + bv.x;
    r.y = p0.y + p1.y + bv.y;
    r.z = p0.z + p1.z + bv.z;
    r.w = p0.w + p1.w + bv.w;
    ((float4*)out)[i4] = r;
}

// ---------------------------------------------------------------------------
extern "C" void kernel_launch(void* const* d_in, const int* in_sizes, int n_in,
                              void* d_out, int out_size, void* d_ws, size_t ws_size,
                              hipStream_t stream)
{
    const float* x     = (const float*)d_in[0]; // [4][1][4096]
    const float* W     = (const float*)d_in[1]; // [11008][4096]
    const float* bias  = (const float*)d_in[2]; // [11008]
    const float* U     = (const float*)d_in[3]; // [11008][512]
    const float* S     = (const float*)d_in[4]; // [512]
    const float* V     = (const float*)d_in[5]; // [4096][512]
    const float* scale = (const float*)d_in[6]; // [4096]
    const float* thp   = (const float*)d_in[7]; // [1]
    float* out = (float*)d_out;                 // [4][1][11008]

    float* partial = (float*)d_ws;                          // 2 MB
    float* lr      = partial + (size_t)NCHUNK * NB * RANK;  // 8 KB
    float* xs      = lr + NB * RANK;                        // 64 KB
    float* part    = xs + NB * DIN;                         // 352 KB

    lr_partial_kernel<<<NCHUNK, 512, 0, stream>>>(x, scale, thp, V, partial, xs);
    lr_reduce_kernel<<<(NB * RANK * 16) / 256, 256, 0, stream>>>(partial, S, lr);

    dim3 grid(DOUT / ROWS_PER_BLOCK, SPLITK); // (688, 2)
    rsparse_main_kernel<<<grid, 256, 0, stream>>>(xs, W, U, lr, part);
    final_add_kernel<<<(NB * DOUT / 4) / 256, 256, 0, stream>>>(part, bias, out);
}

// Round 9
// 47.923 us; speedup vs baseline: 1.4287x; 1.1350x over previous
//
#include <hip/hip_runtime.h>
#include <cmath>

// Problem constants: B=4, T=1, DIN=4096, DOUT=11008, RANK=512
constexpr int DIN  = 4096;
constexpr int DOUT = 11008;
constexpr int RANK = 512;
constexpr int NB   = 4;

constexpr int NCHUNK = 256;          // d-chunks for lr partials
constexpr int DCH    = DIN / NCHUNK; // 16 d's per chunk

constexpr int SPLITK = 2;
constexpr int ROWS   = 8;            // rows per block
constexpr int CHUNK  = 256;          // floats per chunk per row
constexpr int CH4    = CHUNK / 4;    // 64 float4
constexpr int NCH    = DIN / SPLITK / CHUNK; // 8 chunks per k-half

#define GLOAD_LDS16(gsrc, ldst)                                                   \
    __builtin_amdgcn_global_load_lds(                                             \
        (const __attribute__((address_space(1))) void*)(gsrc),                    \
        (__attribute__((address_space(3))) void*)(ldst), 16, 0, 0)

// ---------------------------------------------------------------------------
// Phase 1 (fused prep): xs[b][d] = x*mask -> ws;  xc = x*(1-mask) -> LDS;
// partial[chunk][b][r] = sum_{d in chunk} xc[b][d] * V[d][r]
// ---------------------------------------------------------------------------
__global__ __launch_bounds__(512)
void lr_partial_kernel(const float* __restrict__ x,
                       const float* __restrict__ scale,
                       const float* __restrict__ thp,
                       const float* __restrict__ V,
                       float* __restrict__ partial,
                       float* __restrict__ xs)
{
    __shared__ float xc[NB * DCH];
    const int chunk = blockIdx.x;
    const int t = threadIdx.x;
    const float th = thp[0];
    if (t < NB * DCH) {
        const int b = t / DCH, dd = t % DCH;
        const int d = chunk * DCH + dd;
        const float xv = x[b * DIN + d];
        const bool keep = fabsf(xv * scale[d]) > th; // mask==1 -> sparse path
        xc[t] = keep ? 0.f : xv;
        xs[b * DIN + d] = keep ? xv : 0.f;
    }
    __syncthreads();
    const int r = t; // 0..511
    float a0 = 0.f, a1 = 0.f, a2 = 0.f, a3 = 0.f;
    #pragma unroll
    for (int dd = 0; dd < DCH; ++dd) {
        const float v = V[(size_t)(chunk * DCH + dd) * RANK + r];
        a0 = fmaf(xc[0 * DCH + dd], v, a0);
        a1 = fmaf(xc[1 * DCH + dd], v, a1);
        a2 = fmaf(xc[2 * DCH + dd], v, a2);
        a3 = fmaf(xc[3 * DCH + dd], v, a3);
    }
    float* p = partial + (size_t)chunk * (NB * RANK) + r;
    p[0 * RANK] = a0;
    p[1 * RANK] = a1;
    p[2 * RANK] = a2;
    p[3 * RANK] = a3;
}

// ---------------------------------------------------------------------------
// Phase 2: lr[b][r] = S[r] * sum_chunk partial[chunk][b][r]
// ---------------------------------------------------------------------------
__global__ __launch_bounds__(256)
void lr_reduce_kernel(const float* __restrict__ partial,
                      const float* __restrict__ S,
                      float* __restrict__ lr)
{
    const int t = blockIdx.x * 256 + threadIdx.x;
    const int idx = t >> 4;  // output index 0..NB*RANK-1
    const int s = t & 15;    // chunk-subset
    float sum = 0.f;
    #pragma unroll
    for (int j = 0; j < 16; ++j)
        sum += partial[(size_t)(s * 16 + j) * (NB * RANK) + idx];
    #pragma unroll
    for (int m = 8; m >= 1; m >>= 1)
        sum += __shfl_xor(sum, m, 64);
    if (s == 0)
        lr[idx] = sum * S[idx & (RANK - 1)];
}

// ---------------------------------------------------------------------------
// Main: global_load_lds-staged W, 2-phase double-buffered (T3 minimal).
//   part[kh][b][o] = sum_{d in half kh} xs[b][d]*W[o][d]  (+ U.lr for kh==0)
// Block = 4 waves, 8 rows, one k-half. LDS = 2 x 8 KB. Per chunk-iter/wave:
// 2 global_load_lds (next chunk) + 2 ds_read_b128 + 4 xs loads + 32 FMA.
// W bytes never touch VGPRs; ~64 KB staged-ahead per CU (8 blocks x 8 KB).
// ---------------------------------------------------------------------------
__global__ __launch_bounds__(256)
void rsparse_main_kernel(const float* __restrict__ xs,
                         const float* __restrict__ W,
                         const float* __restrict__ U,
                         const float* __restrict__ lr,
                         float* __restrict__ part)
{
    __shared__ float sbuf[2 * ROWS * CHUNK]; // 16 KB
    const int tid  = threadIdx.x;
    const int wave = tid >> 6, lane = tid & 63;
    const int kh   = blockIdx.y;
    const int o0   = blockIdx.x * ROWS;
    const int kofs = kh * (DIN / SPLITK);    // float offset of this half
    const int r0   = wave * 2, r1 = r0 + 1;  // this wave's rows

    const float4* __restrict__ XS = (const float4*)xs; // [NB][1024]
    const int xbase4 = kofs / 4;

    // ---- stage chunk c into buffer `buf` (this wave's 2 rows) ----
    auto STAGE = [&](int buf, int c) {
        const float* s0 = W + (size_t)(o0 + r0) * DIN + kofs + c * CHUNK + lane * 4;
        const float* s1 = W + (size_t)(o0 + r1) * DIN + kofs + c * CHUNK + lane * 4;
        GLOAD_LDS16(s0, &sbuf[buf * (ROWS * CHUNK) + r0 * CHUNK]);
        GLOAD_LDS16(s1, &sbuf[buf * (ROWS * CHUNK) + r1 * CHUNK]);
    };

    float acc0[NB] = {0.f, 0.f, 0.f, 0.f};
    float acc1[NB] = {0.f, 0.f, 0.f, 0.f};

    STAGE(0, 0);
    __syncthreads(); // drains vmcnt(0): buffer 0 complete for all waves

    int cur = 0;
    for (int c = 0; c < NCH; ++c) {
        if (c + 1 < NCH)
            STAGE(cur ^ 1, c + 1); // issue next chunk before compute

        const float4* wb = (const float4*)&sbuf[cur * (ROWS * CHUNK)];
        const float4 w0 = wb[r0 * CH4 + lane];
        const float4 w1 = wb[r1 * CH4 + lane];
        const int x4 = xbase4 + c * CH4 + lane;
        #pragma unroll
        for (int b = 0; b < NB; ++b) {
            const float4 xv = XS[b * 1024 + x4];
            acc0[b] = fmaf(w0.x, xv.x, acc0[b]);
            acc0[b] = fmaf(w0.y, xv.y, acc0[b]);
            acc0[b] = fmaf(w0.z, xv.z, acc0[b]);
            acc0[b] = fmaf(w0.w, xv.w, acc0[b]);
            acc1[b] = fmaf(w1.x, xv.x, acc1[b]);
            acc1[b] = fmaf(w1.y, xv.y, acc1[b]);
            acc1[b] = fmaf(w1.z, xv.z, acc1[b]);
            acc1[b] = fmaf(w1.w, xv.w, acc1[b]);
        }

        __syncthreads(); // drains vmcnt -> buf cur^1 complete; cur reusable
        cur ^= 1;
    }

    if (kh == 0) { // U.lr compensation for this wave's 2 rows
        const float4* __restrict__ U0 = (const float4*)(U + (size_t)(o0 + r0) * RANK);
        const float4* __restrict__ U1 = (const float4*)(U + (size_t)(o0 + r1) * RANK);
        const float4* __restrict__ LR = (const float4*)lr; // [NB][128]
        #pragma unroll
        for (int j = 0; j < 2; ++j) {
            const int c = (j << 6) + lane; // 0..127
            const float4 u0 = U0[c];
            const float4 u1 = U1[c];
            #pragma unroll
            for (int b = 0; b < NB; ++b) {
                const float4 lv = LR[b * 128 + c];
                acc0[b] = fmaf(u0.x, lv.x, acc0[b]);
                acc0[b] = fmaf(u0.y, lv.y, acc0[b]);
                acc0[b] = fmaf(u0.z, lv.z, acc0[b]);
                acc0[b] = fmaf(u0.w, lv.w, acc0[b]);
                acc1[b] = fmaf(u1.x, lv.x, acc1[b]);
                acc1[b] = fmaf(u1.y, lv.y, acc1[b]);
                acc1[b] = fmaf(u1.z, lv.z, acc1[b]);
                acc1[b] = fmaf(u1.w, lv.w, acc1[b]);
            }
        }
    }

    // 64-lane butterfly reduction
    #pragma unroll
    for (int b = 0; b < NB; ++b) {
        #pragma unroll
        for (int m = 32; m >= 1; m >>= 1) {
            acc0[b] += __shfl_xor(acc0[b], m, 64);
            acc1[b] += __shfl_xor(acc1[b], m, 64);
        }
    }

    if (lane == 0) {
        float* p = part + (size_t)kh * (NB * DOUT);
        #pragma unroll
        for (int b = 0; b < NB; ++b) {
            p[b * DOUT + o0 + r0] = acc0[b];
            p[b * DOUT + o0 + r1] = acc1[b];
        }
    }
}

// ---------------------------------------------------------------------------
// Final: out[b][o] = part[0][b][o] + part[1][b][o] + bias[o]  (float4)
// ---------------------------------------------------------------------------
__global__ __launch_bounds__(256)
void final_add_kernel(const float* __restrict__ part,
                      const float* __restrict__ bias,
                      float* __restrict__ out)
{
    const int i4 = blockIdx.x * 256 + threadIdx.x; // 0..NB*DOUT/4-1
    const int o4 = i4 % (DOUT / 4);
    const float4 p0 = ((const float4*)part)[i4];
    const float4 p1 = ((const float4*)part)[NB * DOUT / 4 + i4];
    const float4 bv = ((const float4*)bias)[o4];
    float4 r;
    r.x = p0.x + p1.x + bv.x;
    r.y = p0.y + p1.y + bv.y;
    r.z = p0.z + p1.z + bv.z;
    r.w = p0.w + p1.w + bv.w;
    ((float4*)out)[i4] = r;
}

// ---------------------------------------------------------------------------
extern "C" void kernel_launch(void* const* d_in, const int* in_sizes, int n_in,
                              void* d_out, int out_size, void* d_ws, size_t ws_size,
                              hipStream_t stream)
{
    const float* x     = (const float*)d_in[0]; // [4][1][4096]
    const float* W     = (const float*)d_in[1]; // [11008][4096]
    const float* bias  = (const float*)d_in[2]; // [11008]
    const float* U     = (const float*)d_in[3]; // [11008][512]
    const float* S     = (const float*)d_in[4]; // [512]
    const float* V     = (const float*)d_in[5]; // [4096][512]
    const float* scale = (const float*)d_in[6]; // [4096]
    const float* thp   = (const float*)d_in[7]; // [1]
    float* out = (float*)d_out;                 // [4][1][11008]

    float* partial = (float*)d_ws;                          // 2 MB
    float* lr      = partial + (size_t)NCHUNK * NB * RANK;  // 8 KB
    float* xs      = lr + NB * RANK;                        // 64 KB
    float* part    = xs + NB * DIN;                         // 352 KB

    lr_partial_kernel<<<NCHUNK, 512, 0, stream>>>(x, scale, thp, V, partial, xs);
    lr_reduce_kernel<<<(NB * RANK * 16) / 256, 256, 0, stream>>>(partial, S, lr);

    dim3 grid(DOUT / ROWS, SPLITK); // (1376, 2)
    rsparse_main_kernel<<<grid, 256, 0, stream>>>(xs, W, U, lr, part);
    final_add_kernel<<<(NB * DOUT / 4) / 256, 256, 0, stream>>>(part, bias, out);
}

// Round 10
// 47.881 us; speedup vs baseline: 1.4299x; 1.0009x over previous
//
#include <hip/hip_runtime.h>
#include <cmath>

// Problem constants: B=4, T=1, DIN=4096, DOUT=11008, RANK=512
constexpr int DIN  = 4096;
constexpr int DOUT = 11008;
constexpr int RANK = 512;
constexpr int NB   = 4;

constexpr int NCHUNK = 256;          // d-chunks for lr partials
constexpr int DCH    = DIN / NCHUNK; // 16 d's per chunk

constexpr int SPLITK = 2;
constexpr int ROWS   = 8;            // rows per block (4 waves x 2 rows)
constexpr int CHUNK  = 256;          // floats per chunk per row (1 gload_lds16/row)
constexpr int CH4    = CHUNK / 4;    // 64 float4
constexpr int NCH    = DIN / SPLITK / CHUNK; // 8 chunks per k-half
constexpr int NBUF   = 3;            // LDS pipeline depth (2-ahead prefetch)

#define GLOAD_LDS16(gsrc, ldst)                                                   \
    __builtin_amdgcn_global_load_lds(                                             \
        (const __attribute__((address_space(1))) void*)(gsrc),                    \
        (__attribute__((address_space(3))) void*)(ldst), 16, 0, 0)

#define WAITV(n) asm volatile("s_waitcnt vmcnt(" #n ")" ::: "memory")

// ---------------------------------------------------------------------------
// Phase 1 (fused prep): xs[b][d] = x*mask -> ws;  xc = x*(1-mask) -> LDS;
// partial[chunk][b][r] = sum_{d in chunk} xc[b][d] * V[d][r]
// ---------------------------------------------------------------------------
__global__ __launch_bounds__(512)
void lr_partial_kernel(const float* __restrict__ x,
                       const float* __restrict__ scale,
                       const float* __restrict__ thp,
                       const float* __restrict__ V,
                       float* __restrict__ partial,
                       float* __restrict__ xs)
{
    __shared__ float xc[NB * DCH];
    const int chunk = blockIdx.x;
    const int t = threadIdx.x;
    const float th = thp[0];
    if (t < NB * DCH) {
        const int b = t / DCH, dd = t % DCH;
        const int d = chunk * DCH + dd;
        const float xv = x[b * DIN + d];
        const bool keep = fabsf(xv * scale[d]) > th; // mask==1 -> sparse path
        xc[t] = keep ? 0.f : xv;
        xs[b * DIN + d] = keep ? xv : 0.f;
    }
    __syncthreads();
    const int r = t; // 0..511
    float a0 = 0.f, a1 = 0.f, a2 = 0.f, a3 = 0.f;
    #pragma unroll
    for (int dd = 0; dd < DCH; ++dd) {
        const float v = V[(size_t)(chunk * DCH + dd) * RANK + r];
        a0 = fmaf(xc[0 * DCH + dd], v, a0);
        a1 = fmaf(xc[1 * DCH + dd], v, a1);
        a2 = fmaf(xc[2 * DCH + dd], v, a2);
        a3 = fmaf(xc[3 * DCH + dd], v, a3);
    }
    float* p = partial + (size_t)chunk * (NB * RANK) + r;
    p[0 * RANK] = a0;
    p[1 * RANK] = a1;
    p[2 * RANK] = a2;
    p[3 * RANK] = a3;
}

// ---------------------------------------------------------------------------
// Phase 2: lr[b][r] = S[r] * sum_chunk partial[chunk][b][r]
// ---------------------------------------------------------------------------
__global__ __launch_bounds__(256)
void lr_reduce_kernel(const float* __restrict__ partial,
                      const float* __restrict__ S,
                      float* __restrict__ lr)
{
    const int t = blockIdx.x * 256 + threadIdx.x;
    const int idx = t >> 4;  // output index 0..NB*RANK-1
    const int s = t & 15;    // chunk-subset
    float sum = 0.f;
    #pragma unroll
    for (int j = 0; j < 16; ++j)
        sum += partial[(size_t)(s * 16 + j) * (NB * RANK) + idx];
    #pragma unroll
    for (int m = 8; m >= 1; m >>= 1)
        sum += __shfl_xor(sum, m, 64);
    if (s == 0)
        lr[idx] = sum * S[idx & (RANK - 1)];
}

// ---------------------------------------------------------------------------
// Main: barrier-FREE global_load_lds pipeline with counted vmcnt (T4).
// Each wave stages and reads ONLY its own 2 LDS rows -> no cross-wave LDS
// dependency -> no __syncthreads needed. NBUF=3, prefetch 2 chunks ahead;
// steady-state s_waitcnt vmcnt(4) keeps 2 buffers (4 loads) in flight
// across compute. LDS 24 KB -> 6 blocks/CU = 24 waves/CU.
// ---------------------------------------------------------------------------
__global__ __launch_bounds__(256)
void rsparse_main_kernel(const float* __restrict__ xs,
                         const float* __restrict__ W,
                         const float* __restrict__ U,
                         const float* __restrict__ lr,
                         float* __restrict__ part)
{
    __shared__ float sbuf[NBUF * ROWS * CHUNK]; // 24 KB
    const int tid  = threadIdx.x;
    const int wave = tid >> 6, lane = tid & 63;
    const int kh   = blockIdx.y;
    const int o0   = blockIdx.x * ROWS;
    const int kofs = kh * (DIN / SPLITK);    // float offset of this half
    const int r0   = wave * 2, r1 = r0 + 1;  // this wave's rows

    const float4* __restrict__ XS = (const float4*)xs; // [NB][1024]
    const int xbase4 = kofs / 4;

    const float* Wr0 = W + (size_t)(o0 + r0) * DIN + kofs + lane * 4;
    const float* Wr1 = W + (size_t)(o0 + r1) * DIN + kofs + lane * 4;

    // stage chunk c into buffer slot `buf` (this wave's 2 rows only)
    auto STAGE = [&](int buf, int c) {
        GLOAD_LDS16(Wr0 + c * CHUNK, &sbuf[buf * (ROWS * CHUNK) + r0 * CHUNK]);
        GLOAD_LDS16(Wr1 + c * CHUNK, &sbuf[buf * (ROWS * CHUNK) + r1 * CHUNK]);
    };

    float acc0[NB] = {0.f, 0.f, 0.f, 0.f};
    float acc1[NB] = {0.f, 0.f, 0.f, 0.f};

    STAGE(0, 0);
    STAGE(1, 1);

    #pragma unroll
    for (int c = 0; c < NCH; ++c) {
        if (c + 2 < NCH)
            STAGE((c + 2) % NBUF, c + 2);

        // wait until buffer c's 2 loads have landed; keep newer loads in flight
        const int ahead = (NCH - 1 - c) < 2 ? (NCH - 1 - c) : 2;
        if (ahead == 2)      WAITV(4);
        else if (ahead == 1) WAITV(2);
        else                 WAITV(0);
        __builtin_amdgcn_sched_barrier(0); // fence: no hoisting across the wait

        const float4* wb = (const float4*)&sbuf[(c % NBUF) * (ROWS * CHUNK)];
        const float4 w0 = wb[r0 * CH4 + lane];
        const float4 w1 = wb[r1 * CH4 + lane];
        const int x4 = xbase4 + c * CH4 + lane;
        #pragma unroll
        for (int b = 0; b < NB; ++b) {
            const float4 xv = XS[b * 1024 + x4];
            acc0[b] = fmaf(w0.x, xv.x, acc0[b]);
            acc0[b] = fmaf(w0.y, xv.y, acc0[b]);
            acc0[b] = fmaf(w0.z, xv.z, acc0[b]);
            acc0[b] = fmaf(w0.w, xv.w, acc0[b]);
            acc1[b] = fmaf(w1.x, xv.x, acc1[b]);
            acc1[b] = fmaf(w1.y, xv.y, acc1[b]);
            acc1[b] = fmaf(w1.z, xv.z, acc1[b]);
            acc1[b] = fmaf(w1.w, xv.w, acc1[b]);
        }
    }

    if (kh == 0) { // U.lr compensation for this wave's 2 rows
        const float4* __restrict__ U0 = (const float4*)(U + (size_t)(o0 + r0) * RANK);
        const float4* __restrict__ U1 = (const float4*)(U + (size_t)(o0 + r1) * RANK);
        const float4* __restrict__ LR = (const float4*)lr; // [NB][128]
        #pragma unroll
        for (int j = 0; j < 2; ++j) {
            const int c = (j << 6) + lane; // 0..127
            const float4 u0 = U0[c];
            const float4 u1 = U1[c];
            #pragma unroll
            for (int b = 0; b < NB; ++b) {
                const float4 lv = LR[b * 128 + c];
                acc0[b] = fmaf(u0.x, lv.x, acc0[b]);
                acc0[b] = fmaf(u0.y, lv.y, acc0[b]);
                acc0[b] = fmaf(u0.z, lv.z, acc0[b]);
                acc0[b] = fmaf(u0.w, lv.w, acc0[b]);
                acc1[b] = fmaf(u1.x, lv.x, acc1[b]);
                acc1[b] = fmaf(u1.y, lv.y, acc1[b]);
                acc1[b] = fmaf(u1.z, lv.z, acc1[b]);
                acc1[b] = fmaf(u1.w, lv.w, acc1[b]);
            }
        }
    }

    // 64-lane butterfly reduction
    #pragma unroll
    for (int b = 0; b < NB; ++b) {
        #pragma unroll
        for (int m = 32; m >= 1; m >>= 1) {
            acc0[b] += __shfl_xor(acc0[b], m, 64);
            acc1[b] += __shfl_xor(acc1[b], m, 64);
        }
    }

    if (lane == 0) {
        float* p = part + (size_t)kh * (NB * DOUT);
        #pragma unroll
        for (int b = 0; b < NB; ++b) {
            p[b * DOUT + o0 + r0] = acc0[b];
            p[b * DOUT + o0 + r1] = acc1[b];
        }
    }
}

// ---------------------------------------------------------------------------
// Final: out[b][o] = part[0][b][o] + part[1][b][o] + bias[o]  (float4)
// ---------------------------------------------------------------------------
__global__ __launch_bounds__(256)
void final_add_kernel(const float* __restrict__ part,
                      const float* __restrict__ bias,
                      float* __restrict__ out)
{
    const int i4 = blockIdx.x * 256 + threadIdx.x; // 0..NB*DOUT/4-1
    const int o4 = i4 % (DOUT / 4);
    const float4 p0 = ((const float4*)part)[i4];
    const float4 p1 = ((const float4*)part)[NB * DOUT / 4 + i4];
    const float4 bv = ((const float4*)bias)[o4];
    float4 r;
    r.x = p0.x + p1.x + bv.x;
    r.y = p0.y + p1.y + bv.y;
    r.z = p0.z + p1.z + bv.z;
    r.w = p0.w + p1.w + bv.w;
    ((float4*)out)[i4] = r;
}

// ---------------------------------------------------------------------------
extern "C" void kernel_launch(void* const* d_in, const int* in_sizes, int n_in,
                              void* d_out, int out_size, void* d_ws, size_t ws_size,
                              hipStream_t stream)
{
    const float* x     = (const float*)d_in[0]; // [4][1][4096]
    const float* W     = (const float*)d_in[1]; // [11008][4096]
    const float* bias  = (const float*)d_in[2]; // [11008]
    const float* U     = (const float*)d_in[3]; // [11008][512]
    const float* S     = (const float*)d_in[4]; // [512]
    const float* V     = (const float*)d_in[5]; // [4096][512]
    const float* scale = (const float*)d_in[6]; // [4096]
    const float* thp   = (const float*)d_in[7]; // [1]
    float* out = (float*)d_out;                 // [4][1][11008]

    float* partial = (float*)d_ws;                          // 2 MB
    float* lr      = partial + (size_t)NCHUNK * NB * RANK;  // 8 KB
    float* xs      = lr + NB * RANK;                        // 64 KB
    float* part    = xs + NB * DIN;                         // 352 KB

    lr_partial_kernel<<<NCHUNK, 512, 0, stream>>>(x, scale, thp, V, partial, xs);
    lr_reduce_kernel<<<(NB * RANK * 16) / 256, 256, 0, stream>>>(partial, S, lr);

    dim3 grid(DOUT / ROWS, SPLITK); // (1376, 2)
    rsparse_main_kernel<<<grid, 256, 0, stream>>>(xs, W, U, lr, part);
    final_add_kernel<<<(NB * DOUT / 4) / 256, 256, 0, stream>>>(part, bias, out);
}

// Round 11
// 46.966 us; speedup vs baseline: 1.4578x; 1.0195x over previous
//
#include <hip/hip_runtime.h>
#include <cmath>

// Problem constants: B=4, T=1, DIN=4096, DOUT=11008, RANK=512
constexpr int DIN  = 4096;
constexpr int DOUT = 11008;
constexpr int RANK = 512;
constexpr int NB   = 4;

constexpr int NCHUNK = 256;          // d-chunks for lr partials
constexpr int DCH    = DIN / NCHUNK; // 16 d's per chunk

constexpr int ROWS   = 8;            // rows per block (4 waves x 2 rows)
constexpr int CHUNK  = 256;          // floats per chunk per row (1 gload_lds16/row)
constexpr int CH4    = CHUNK / 4;    // 64 float4
constexpr int NCH    = DIN / CHUNK;  // 16 chunks (full K, no split)
constexpr int NBUF   = 4;            // LDS pipeline depth (3-ahead prefetch)

#define GLOAD_LDS16(gsrc, ldst)                                                   \
    __builtin_amdgcn_global_load_lds(                                             \
        (const __attribute__((address_space(1))) void*)(gsrc),                    \
        (__attribute__((address_space(3))) void*)(ldst), 16, 0, 0)

#define WAITV(n) asm volatile("s_waitcnt vmcnt(" #n ")" ::: "memory")

// ---------------------------------------------------------------------------
// Phase 1 (fused prep): xs[b][d] = x*mask -> ws;  xc = x*(1-mask) -> LDS;
// partial[chunk][b][r] = sum_{d in chunk} xc[b][d] * V[d][r]
// ---------------------------------------------------------------------------
__global__ __launch_bounds__(512)
void lr_partial_kernel(const float* __restrict__ x,
                       const float* __restrict__ scale,
                       const float* __restrict__ thp,
                       const float* __restrict__ V,
                       float* __restrict__ partial,
                       float* __restrict__ xs)
{
    __shared__ float xc[NB * DCH];
    const int chunk = blockIdx.x;
    const int t = threadIdx.x;
    const float th = thp[0];
    if (t < NB * DCH) {
        const int b = t / DCH, dd = t % DCH;
        const int d = chunk * DCH + dd;
        const float xv = x[b * DIN + d];
        const bool keep = fabsf(xv * scale[d]) > th; // mask==1 -> sparse path
        xc[t] = keep ? 0.f : xv;
        xs[b * DIN + d] = keep ? xv : 0.f;
    }
    __syncthreads();
    const int r = t; // 0..511
    float a0 = 0.f, a1 = 0.f, a2 = 0.f, a3 = 0.f;
    #pragma unroll
    for (int dd = 0; dd < DCH; ++dd) {
        const float v = V[(size_t)(chunk * DCH + dd) * RANK + r];
        a0 = fmaf(xc[0 * DCH + dd], v, a0);
        a1 = fmaf(xc[1 * DCH + dd], v, a1);
        a2 = fmaf(xc[2 * DCH + dd], v, a2);
        a3 = fmaf(xc[3 * DCH + dd], v, a3);
    }
    float* p = partial + (size_t)chunk * (NB * RANK) + r;
    p[0 * RANK] = a0;
    p[1 * RANK] = a1;
    p[2 * RANK] = a2;
    p[3 * RANK] = a3;
}

// ---------------------------------------------------------------------------
// Phase 2: lr[b][r] = S[r] * sum_chunk partial[chunk][b][r]
// ---------------------------------------------------------------------------
__global__ __launch_bounds__(256)
void lr_reduce_kernel(const float* __restrict__ partial,
                      const float* __restrict__ S,
                      float* __restrict__ lr)
{
    const int t = blockIdx.x * 256 + threadIdx.x;
    const int idx = t >> 4;  // output index 0..NB*RANK-1
    const int s = t & 15;    // chunk-subset
    float sum = 0.f;
    #pragma unroll
    for (int j = 0; j < 16; ++j)
        sum += partial[(size_t)(s * 16 + j) * (NB * RANK) + idx];
    #pragma unroll
    for (int m = 8; m >= 1; m >>= 1)
        sum += __shfl_xor(sum, m, 64);
    if (s == 0)
        lr[idx] = sum * S[idx & (RANK - 1)];
}

// ---------------------------------------------------------------------------
// Main (full-K, direct output): out[b][o] = bias[o] + sum_d xs[b][d]*W[o][d]
//                                           + sum_r lr[b][r]*U[o][r]
// Barrier-free global_load_lds pipeline, counted vmcnt, NBUF=4, 3-ahead.
// Each wave owns 2 rows end-to-end; no cross-wave LDS dependency.
// LDS 32 KB -> 5 blocks/CU = 20 waves/CU; 6 KB in flight per wave.
// ---------------------------------------------------------------------------
__global__ __launch_bounds__(256)
void rsparse_main_kernel(const float* __restrict__ xs,
                         const float* __restrict__ W,
                         const float* __restrict__ U,
                         const float* __restrict__ lr,
                         const float* __restrict__ bias,
                         float* __restrict__ out)
{
    __shared__ float sbuf[NBUF * ROWS * CHUNK]; // 32 KB
    const int tid  = threadIdx.x;
    const int wave = tid >> 6, lane = tid & 63;
    const int o0   = blockIdx.x * ROWS;
    const int r0   = wave * 2, r1 = r0 + 1;  // this wave's rows

    const float4* __restrict__ XS = (const float4*)xs; // [NB][1024]

    const float* Wr0 = W + (size_t)(o0 + r0) * DIN + lane * 4;
    const float* Wr1 = W + (size_t)(o0 + r1) * DIN + lane * 4;

    // stage chunk c into buffer slot `buf` (this wave's 2 rows only)
    auto STAGE = [&](int buf, int c) {
        GLOAD_LDS16(Wr0 + c * CHUNK, &sbuf[buf * (ROWS * CHUNK) + r0 * CHUNK]);
        GLOAD_LDS16(Wr1 + c * CHUNK, &sbuf[buf * (ROWS * CHUNK) + r1 * CHUNK]);
    };

    float acc0[NB] = {0.f, 0.f, 0.f, 0.f};
    float acc1[NB] = {0.f, 0.f, 0.f, 0.f};

    STAGE(0, 0);
    STAGE(1, 1);
    STAGE(2, 2);

    #pragma unroll
    for (int c = 0; c < NCH; ++c) {
        if (c + 3 < NCH)
            STAGE((c + 3) & (NBUF - 1), c + 3);

        // wait until chunk c's 2 loads landed; keep newer chunks in flight
        if (c < NCH - 3)       WAITV(6);
        else if (c == NCH - 3) WAITV(4);
        else if (c == NCH - 2) WAITV(2);
        else                   WAITV(0);
        __builtin_amdgcn_sched_barrier(0); // no hoisting across the wait

        const float4* wb = (const float4*)&sbuf[(c & (NBUF - 1)) * (ROWS * CHUNK)];
        const float4 w0 = wb[r0 * CH4 + lane];
        const float4 w1 = wb[r1 * CH4 + lane];
        const int x4 = c * CH4 + lane;
        #pragma unroll
        for (int b = 0; b < NB; ++b) {
            const float4 xv = XS[b * 1024 + x4];
            acc0[b] = fmaf(w0.x, xv.x, acc0[b]);
            acc0[b] = fmaf(w0.y, xv.y, acc0[b]);
            acc0[b] = fmaf(w0.z, xv.z, acc0[b]);
            acc0[b] = fmaf(w0.w, xv.w, acc0[b]);
            acc1[b] = fmaf(w1.x, xv.x, acc1[b]);
            acc1[b] = fmaf(w1.y, xv.y, acc1[b]);
            acc1[b] = fmaf(w1.z, xv.z, acc1[b]);
            acc1[b] = fmaf(w1.w, xv.w, acc1[b]);
        }
    }

    { // U.lr compensation for this wave's 2 rows
        const float4* __restrict__ U0 = (const float4*)(U + (size_t)(o0 + r0) * RANK);
        const float4* __restrict__ U1 = (const float4*)(U + (size_t)(o0 + r1) * RANK);
        const float4* __restrict__ LR = (const float4*)lr; // [NB][128]
        #pragma unroll
        for (int j = 0; j < 2; ++j) {
            const int c = (j << 6) + lane; // 0..127
            const float4 u0 = U0[c];
            const float4 u1 = U1[c];
            #pragma unroll
            for (int b = 0; b < NB; ++b) {
                const float4 lv = LR[b * 128 + c];
                acc0[b] = fmaf(u0.x, lv.x, acc0[b]);
                acc0[b] = fmaf(u0.y, lv.y, acc0[b]);
                acc0[b] = fmaf(u0.z, lv.z, acc0[b]);
                acc0[b] = fmaf(u0.w, lv.w, acc0[b]);
                acc1[b] = fmaf(u1.x, lv.x, acc1[b]);
                acc1[b] = fmaf(u1.y, lv.y, acc1[b]);
                acc1[b] = fmaf(u1.z, lv.z, acc1[b]);
                acc1[b] = fmaf(u1.w, lv.w, acc1[b]);
            }
        }
    }

    // 64-lane butterfly reduction
    #pragma unroll
    for (int b = 0; b < NB; ++b) {
        #pragma unroll
        for (int m = 32; m >= 1; m >>= 1) {
            acc0[b] += __shfl_xor(acc0[b], m, 64);
            acc1[b] += __shfl_xor(acc1[b], m, 64);
        }
    }

    if (lane == 0) {
        const float bi0 = bias[o0 + r0], bi1 = bias[o0 + r1];
        #pragma unroll
        for (int b = 0; b < NB; ++b) {
            out[b * DOUT + o0 + r0] = acc0[b] + bi0;
            out[b * DOUT + o0 + r1] = acc1[b] + bi1;
        }
    }
}

// ---------------------------------------------------------------------------
extern "C" void kernel_launch(void* const* d_in, const int* in_sizes, int n_in,
                              void* d_out, int out_size, void* d_ws, size_t ws_size,
                              hipStream_t stream)
{
    const float* x     = (const float*)d_in[0]; // [4][1][4096]
    const float* W     = (const float*)d_in[1]; // [11008][4096]
    const float* bias  = (const float*)d_in[2]; // [11008]
    const float* U     = (const float*)d_in[3]; // [11008][512]
    const float* S     = (const float*)d_in[4]; // [512]
    const float* V     = (const float*)d_in[5]; // [4096][512]
    const float* scale = (const float*)d_in[6]; // [4096]
    const float* thp   = (const float*)d_in[7]; // [1]
    float* out = (float*)d_out;                 // [4][1][11008]

    float* partial = (float*)d_ws;                          // 2 MB
    float* lr      = partial + (size_t)NCHUNK * NB * RANK;  // 8 KB
    float* xs      = lr + NB * RANK;                        // 64 KB

    lr_partial_kernel<<<NCHUNK, 512, 0, stream>>>(x, scale, thp, V, partial, xs);
    lr_reduce_kernel<<<(NB * RANK * 16) / 256, 256, 0, stream>>>(partial, S, lr);
    rsparse_main_kernel<<<DOUT / ROWS, 256, 0, stream>>>(xs, W, U, lr, bias, out);
}